// Round 10
// baseline (374.329 us; speedup 1.0000x reference)
//
#include <hip/hip_runtime.h>

// ---------- types ----------
typedef float  f32x4 __attribute__((ext_vector_type(4)));
typedef short  s16x8 __attribute__((ext_vector_type(8)));
typedef __bf16 b16x8 __attribute__((ext_vector_type(8)));
typedef unsigned u32x4 __attribute__((ext_vector_type(4)));

#define DEV __device__ __forceinline__

DEV unsigned short f2b(float f) {           // fp32 -> bf16 RNE
  unsigned u = __builtin_bit_cast(unsigned, f);
  u = (u + 0x7FFFu + ((u >> 16) & 1u)) >> 16;
  return (unsigned short)u;
}
DEV unsigned cvt_pk_bf16(float lo, float hi) {  // packed RNE bf16 pair
  unsigned r;
  asm("v_cvt_pk_bf16_f32 %0, %1, %2" : "=v"(r) : "v"(lo), "v"(hi));
  return r;
}
DEV b16x8 ld8(const unsigned short* p) {    // 16B fragment load + reinterpret
  return __builtin_bit_cast(b16x8, *(const s16x8*)p);
}
DEV float sigm(float x) { return __builtin_amdgcn_rcpf(1.f + __expf(-x)); }
DEV float tanh_fast(float x) {
  float e = __expf(2.f * x);                // overflow-safe: e=inf -> 1, e=0 -> -1
  return 1.f - 2.f * __builtin_amdgcn_rcpf(e + 1.f);
}
DEV f32x4 mfma_bf16(b16x8 a, b16x8 b, f32x4 c) {
  return __builtin_amdgcn_mfma_f32_16x16x32_bf16(a, b, c, 0, 0, 0);
}

// ---------- prep: fp32->bf16 weight conversion, vectorized ----------
// Waug [768][288] = [Whh k-permuted | Wih | bias@271 | 0].
// The k-perm (out 32w+2t+s <- col 32w+t+16s) is a lo/hi zip (two float4 loads
// + 4 cvt_pk per 8-wide item). The SAME perm is applied to the K dims of
// W2/W3/W4 (verified in R4) so the fused MLP stores y activations as packed
// cvt_pk pairs and reads them back as contiguous b128 fragments.
struct PrepArgs {
  const float *whh[2], *wih[2], *bih[2], *bhh[2];
  const float *src[2][4];               // fc1..fc4 fp32 weights per branch
  unsigned short *waug[2], *dst[2][4];  // bf16 outputs
};

template <int ROWS, int SC, int DC>
DEV void prep_fc_pad(const float* __restrict__ src,
                     unsigned short* __restrict__ dst, int i0, int stride) {
  constexpr int IPR = DC / 8;           // items per row (literal divisor)
  for (int i8 = i0; i8 < ROWS * IPR; i8 += stride) {
    const int r = i8 / IPR, it = i8 - r * IPR;
    const int c0 = it * 8;
    u32x4 hp;
    if (c0 + 8 <= SC) {
      const float* bp = src + (size_t)r * SC + c0;
      const float4 a = *(const float4*)bp;
      const float4 b = *(const float4*)(bp + 4);
      hp = u32x4{cvt_pk_bf16(a.x, a.y), cvt_pk_bf16(a.z, a.w),
                 cvt_pk_bf16(b.x, b.y), cvt_pk_bf16(b.z, b.w)};
    } else {
      hp = u32x4{0u, 0u, 0u, 0u};
    }
    *(u32x4*)(dst + (size_t)i8 * 8) = hp;
  }
}

template <int ROWS, int SC>
DEV void prep_fc_perm(const float* __restrict__ src,
                      unsigned short* __restrict__ dst, int i0, int stride) {
  constexpr int IPR = SC / 8;
  for (int i8 = i0; i8 < ROWS * IPR; i8 += stride) {
    const int r = i8 / IPR, it = i8 - r * IPR;
    const int c0 = it * 8;
    const int base32 = c0 & ~31;
    const int ii = (c0 & 31) >> 1;      // 0,4,8,12 -> float4-aligned
    const float* bp = src + (size_t)r * SC + base32 + ii;
    const float4 lo = *(const float4*)bp;
    const float4 hi = *(const float4*)(bp + 16);
    u32x4 hp = {cvt_pk_bf16(lo.x, hi.x), cvt_pk_bf16(lo.y, hi.y),
                cvt_pk_bf16(lo.z, hi.z), cvt_pk_bf16(lo.w, hi.w)};
    *(u32x4*)(dst + (size_t)i8 * 8) = hp;
  }
}

__global__ __launch_bounds__(256) void prep_kernel(PrepArgs p) {
  const int job = blockIdx.y;
  const int i0 = blockIdx.x * 256 + threadIdx.x;   // vec8 item index
  const int stride = gridDim.x * 256;
  if (job < 2) {
    const float* whh = p.whh[job];
    const float* wih = p.wih[job];
    const float* bih = p.bih[job];
    const float* bhh = p.bhh[job];
    unsigned short* dst = p.waug[job];
    for (int i8 = i0; i8 < 768 * 36; i8 += stride) {
      const int j = i8 / 36, it = i8 - j * 36;
      u32x4 hp;
      if (it < 32) {                               // Whh k-permuted (zip)
        const int c0 = it * 8;
        const int base32 = c0 & ~31;
        const int ii = (c0 & 31) >> 1;
        const float* bp = whh + (size_t)j * 256 + base32 + ii;
        const float4 lo = *(const float4*)bp;
        const float4 hi = *(const float4*)(bp + 16);
        hp = u32x4{cvt_pk_bf16(lo.x, hi.x), cvt_pk_bf16(lo.y, hi.y),
                   cvt_pk_bf16(lo.z, hi.z), cvt_pk_bf16(lo.w, hi.w)};
      } else if (it == 32) {                       // cols 256..263 = wih 0..7
        const float* wp = wih + (size_t)j * 15;
        hp = u32x4{cvt_pk_bf16(wp[0], wp[1]), cvt_pk_bf16(wp[2], wp[3]),
                   cvt_pk_bf16(wp[4], wp[5]), cvt_pk_bf16(wp[6], wp[7])};
      } else if (it == 33) {                       // wih 8..14 + bias@271
        const float* wp = wih + (size_t)j * 15;
        const float b271 = (j < 512) ? (bih[j] + bhh[j]) : bih[j];
        hp = u32x4{cvt_pk_bf16(wp[8], wp[9]), cvt_pk_bf16(wp[10], wp[11]),
                   cvt_pk_bf16(wp[12], wp[13]), cvt_pk_bf16(wp[14], b271)};
      } else {                                     // 272..287 zero pad
        hp = u32x4{0u, 0u, 0u, 0u};
      }
      *(u32x4*)(dst + (size_t)i8 * 8) = hp;
    }
  } else if (job == 2) {
    prep_fc_pad<1024, 272, 288>(p.src[0][0], p.dst[0][0], i0, stride);
  } else if (job == 3) {
    prep_fc_perm<1024, 1024>(p.src[0][1], p.dst[0][1], i0, stride);
  } else if (job == 4) {
    prep_fc_perm<512, 1024>(p.src[0][2], p.dst[0][2], i0, stride);
  } else if (job == 5) {
    prep_fc_perm<256, 512>(p.src[0][3], p.dst[0][3], i0, stride);
  } else if (job == 6) {
    prep_fc_pad<1024, 272, 288>(p.src[1][0], p.dst[1][0], i0, stride);
  } else if (job == 7) {
    prep_fc_perm<1024, 1024>(p.src[1][1], p.dst[1][1], i0, stride);
  } else if (job == 8) {
    prep_fc_perm<512, 1024>(p.src[1][2], p.dst[1][2], i0, stride);
  } else {
    prep_fc_perm<256, 512>(p.src[1][3], p.dst[1][3], i0, stride);
  }
}

// ---------- fused GRU + MLP ----------
// 256 blocks x 512 thr; block = (branch g = bid&1, 16 batch rows). gru phase
// is the verified R1/R3 structure (~141 us). fc phase: W fragments loaded
// DIRECTLY TO REGISTERS per lane (the R4-verified mechanism) with a
// distance-1 register double-buffer (wf/wn) -- the compiler's automatic
// vmcnt insertion hides L2 latency under the 4-MFMA block. No LDS for W, no
// inline-asm waitcnt (R8/R9's counted-vmcnt global_load_lds staging was the
// timing-dependent corruption; it was the only unverified mechanism).
// y1/y2/y3 in LDS overlaying the dead gru arena, all transitions barriered.
// g = bid&1, XCD = bid%8 -> one branch's ~3.9 MB of W per XCD = L2-resident.
struct FusedArgs {
  const float *state, *action;
  const int *lengths;
  const unsigned short *waug[2];
  const float *bhh[2];
  const unsigned short *w1[2], *w2[2], *w3[2], *w4[2];
  const float *b1[2], *b2[2], *b3[2], *b4[2], *qw[2], *qb[2];
  float* out;
};

#define FUSED_LDS_BYTES 147968
__global__ __launch_bounds__(512, 2) void fused_kernel(FusedArgs P) {
  extern __shared__ char smem[];
  unsigned short* W67L = (unsigned short*)smem;             // 96 KB arena
  unsigned short* SgL  = (unsigned short*)(smem + 98304);   // 32 KB state frags
  unsigned*       Hb2  = (unsigned*)(smem + 131072);        // 2 x 16 x 128 dw
  int* lenS = (int*)(smem + 147456);
  int* mlS  = (int*)(smem + 147520);
  float* tmpF = (float*)smem;                               // phase-a overlay

  const int tid = threadIdx.x;
  const int lane = tid & 63, w = tid >> 6;
  const int l15 = lane & 15, q = lane >> 4;
  const int g = blockIdx.x & 1;
  const int r0 = (blockIdx.x >> 1) * 16;

  const unsigned short* Waug = P.waug[g];
  const float* bhh = P.bhh[g];

  // ---- phase a: state tile fp32 -> LDS (coalesced, stride-962 rows) ----
  {
    const float2* src = (const float2*)(P.state + (size_t)r0 * 960);
    float2* dstv = (float2*)tmpF;
    for (int i = tid; i < 7680; i += 512) {
      const int row = i / 480;
      dstv[row * 481 + (i - row * 480)] = src[i];
    }
  }
  for (int i = tid; i < 4096; i += 512) Hb2[i] = 0;
  if (tid < 16) lenS[tid] = P.lengths[r0 + tid];
  __syncthreads();
  if (tid == 0) {
    int m = 1;
    for (int i = 0; i < 16; i++) m = lenS[i] > m ? lenS[i] : m;
    *mlS = m;
  }

  // ---- phase b: SgL[t][L] = aug A-fragment (state 15 | 1.0 | 0) ----
  for (int s = tid; s < 64 * 32; s += 512) {
    const int t = s >> 5, L = s & 31;
    const int q2 = L >> 4, r = L & 15;
    const float* bp = tmpF + r * 962 + t * 15;
    unsigned hp[4];
#pragma unroll
    for (int jp = 0; jp < 4; jp++) {
      const int k0 = q2 * 8 + 2 * jp;
      float lo = (k0 < 15) ? bp[k0] : (k0 == 15 ? 1.0f : 0.f);
      float hi = (k0 + 1 < 15) ? bp[k0 + 1] : (k0 + 1 == 15 ? 1.0f : 0.f);
      hp[jp] = cvt_pk_bf16(lo, hi);
    }
    *(u32x4*)(SgL + (size_t)s * 8) = u32x4{hp[0], hp[1], hp[2], hp[3]};
  }
  __syncthreads();  // tmpF dead; arena may be filled

  // ---- phase c: resident weights + arena fill ----
  int c0[6];
  c0[0] = 32 * w;       c0[1] = 32 * w + 16;
  c0[2] = 256 + 32 * w; c0[3] = 256 + 32 * w + 16;
  c0[4] = 512 + 32 * w; c0[5] = 512 + 32 * w + 16;

  b16x8 wres[6][6];
  b16x8 waugf[6];
#pragma unroll
  for (int i = 0; i < 6; i++) {
    const unsigned short* bpi = Waug + (size_t)(c0[i] + l15) * 288 + q * 8;
#pragma unroll
    for (int j = 0; j < 6; j++) wres[i][j] = ld8(bpi + j * 32);
    waugf[i] = ld8(bpi + 256);
#pragma unroll
    for (int ks2 = 0; ks2 < 2; ks2++) {
      b16x8 v = ld8(bpi + (6 + ks2) * 32);
      *(s16x8*)(W67L + (size_t)(ks2 * 6 + i) * 4096 + tid * 8) =
          __builtin_bit_cast(s16x8, v);
    }
  }
  float bnH[2] = {bhh[c0[4] + l15], bhh[c0[5] + l15]};
  int len4[4];
#pragma unroll
  for (int r = 0; r < 4; r++) len4[r] = lenS[q * 4 + r];

  int aOff[8];
#pragma unroll
  for (int j = 0; j < 8; j++) {
    const int cj = 4 * j + q;
    const int pj = (cj & 24) | ((cj & 7) ^ (l15 & 7));
    aOff[j] = l15 * 128 + pj * 4;
  }
  int wOff[4];
#pragma unroll
  for (int rg = 0; rg < 4; rg++) {
    const int row = q * 4 + rg;
    const int cb = 4 * w + (l15 >> 2);
    const int pw = (cb & 24) | ((cb & 7) ^ (row & 7));
    wOff[rg] = row * 128 + pw * 4 + (l15 & 3);
  }
  __syncthreads();
  const int maxlen = *mlS;

  float hold[2][4] = {{0, 0, 0, 0}, {0, 0, 0, 0}};
  int poff = 0;

  for (int t = 0; t < maxlen; ++t) {
    f32x4 acc[6];
    {
      s16x8 raw = *(const s16x8*)(SgL + t * 256 + ((q & 1) * 16 + l15) * 8);
      b16x8 a8 = __builtin_bit_cast(b16x8, raw);
      const f32x4 z4 = {0.f, 0.f, 0.f, 0.f};
#pragma unroll
      for (int i = 0; i < 6; i++) acc[i] = mfma_bf16(a8, waugf[i], z4);
    }
    f32x4 giN0 = acc[4], giN1 = acc[5];
    acc[4] = acc[4] + bnH[0];
    acc[5] = acc[5] + bnH[1];

    __syncthreads();

    const unsigned* hb = Hb2 + poff;
#pragma unroll
    for (int j = 0; j < 6; j++) {
      b16x8 a = __builtin_bit_cast(b16x8, *(const uint4*)(hb + aOff[j]));
#pragma unroll
      for (int i = 0; i < 6; i++) acc[i] = mfma_bf16(a, wres[i][j], acc[i]);
    }
#pragma unroll
    for (int ks2 = 0; ks2 < 2; ks2++) {
      b16x8 a = __builtin_bit_cast(b16x8, *(const uint4*)(hb + aOff[6 + ks2]));
#pragma unroll
      for (int i = 0; i < 6; i++) {
        b16x8 bw = ld8(W67L + (size_t)(ks2 * 6 + i) * 4096 + tid * 8);
        acc[i] = mfma_bf16(a, bw, acc[i]);
      }
    }

    unsigned* hbw = Hb2 + (poff ^ 2048);
#pragma unroll
    for (int rg = 0; rg < 4; rg++) {
      const bool live = (t < len4[rg]);
      float r0g = sigm(acc[0][rg]);
      float z0 = sigm(acc[2][rg]);
      float n0 = tanh_fast(giN0[rg] + r0g * (acc[4][rg] - giN0[rg]));
      float h0 = n0 + z0 * (hold[0][rg] - n0);
      h0 = live ? h0 : hold[0][rg];
      hold[0][rg] = h0;
      float r1g = sigm(acc[1][rg]);
      float z1 = sigm(acc[3][rg]);
      float n1 = tanh_fast(giN1[rg] + r1g * (acc[5][rg] - giN1[rg]));
      float h1 = n1 + z1 * (hold[1][rg] - n1);
      h1 = live ? h1 : hold[1][rg];
      hold[1][rg] = h1;
      hbw[wOff[rg]] = cvt_pk_bf16(h0, h1);
    }
    poff ^= 2048;
  }
  __syncthreads();  // all waves out of the gru loop (arena reads retired)
                    // before Xs overlays the arena region.

  // ================== fc phase ==================
  unsigned* Y1 = (unsigned*)smem;                         // 16 x 512 u32
  unsigned short* Xs = (unsigned short*)(smem + 32768);   // 16 x 296 bf16
  unsigned* Y2 = (unsigned*)(smem + 32768);               // 16 x 512 u32
  unsigned* Y3 = (unsigned*)(smem + 65536);               // 16 x 256 u32
  float* red = (float*)(smem + 147456);                   // [16][8]

  // ---- build Xs [16][296] = [state0 15 | action | h 256 | 0 pad] ----
#pragma unroll
  for (int i = 0; i < 2; i++) {
    const int c = 32 * w + 16 * i + l15;
#pragma unroll
    for (int rg = 0; rg < 4; rg++)
      Xs[(q * 4 + rg) * 296 + 16 + c] = f2b(hold[i][rg]);
  }
  {
    const int row = tid >> 5, cc = tid & 31;
    float v; int col;
    if (cc < 15)       { v = P.state[(size_t)(r0 + row) * 960 + cc]; col = cc; }
    else if (cc == 15) { v = P.action[r0 + row]; col = 15; }
    else               { v = 0.f; col = 256 + cc; }       // 272..287 = 0
    Xs[row * 296 + col] = f2b(v);
  }
  __syncthreads();  // Xs visible block-wide

  auto packY = [&](unsigned* Y, int rowU, int cmask, int n0, const float* bias,
                   f32x4* ac) {
#pragma unroll
    for (int pr = 0; pr < 2; ++pr) {
      const int cLo = n0 + pr * 32 + l15;
      const float bLo = bias[cLo], bHi = bias[cLo + 16];
      const int cb = (n0 >> 3) + pr * 4 + (l15 >> 2);
#pragma unroll
      for (int rg = 0; rg < 4; ++rg) {
        const int R = q * 4 + rg;
        const int pw = (cb & cmask) | ((cb & 7) ^ (R & 7));
        float vLo = fmaxf(ac[2 * pr][rg] + bLo, 0.f);
        float vHi = fmaxf(ac[2 * pr + 1][rg] + bHi, 0.f);
        Y[R * rowU + pw * 4 + (l15 & 3)] = cvt_pk_bf16(vLo, vHi);
      }
    }
  };
  auto aY = [&](const unsigned* Y, int rowU, int cmask, int j) -> b16x8 {
    const int cj = j * 4 + q;
    const int pj = (cj & cmask) | ((cj & 7) ^ (l15 & 7));
    return __builtin_bit_cast(b16x8, *(const uint4*)(Y + l15 * rowU + pj * 4));
  };

  // ---- fc1: Y1 = relu(Xs @ W1^T + b1); K=288 plain; N=1024, 2 passes ----
  {
    const unsigned short* W1 = P.w1[g];
    for (int p = 0; p < 2; ++p) {
      const int n0 = p * 512 + w * 64;
      const unsigned short* w1p = W1 + (size_t)(n0 + l15) * 288 + q * 8;
      f32x4 ac[4];
#pragma unroll
      for (int nt = 0; nt < 4; ++nt) ac[nt] = f32x4{0.f, 0.f, 0.f, 0.f};
      b16x8 wf[4], wn[4];
#pragma unroll
      for (int nt = 0; nt < 4; ++nt) wf[nt] = ld8(w1p + nt * 16 * 288);
      for (int j = 0; j < 9; ++j) {
        if (j + 1 < 9) {
#pragma unroll
          for (int nt = 0; nt < 4; ++nt)
            wn[nt] = ld8(w1p + nt * 16 * 288 + (j + 1) * 32);
        }
        b16x8 a = ld8(Xs + l15 * 296 + j * 32 + q * 8);
#pragma unroll
        for (int nt = 0; nt < 4; ++nt) ac[nt] = mfma_bf16(a, wf[nt], ac[nt]);
#pragma unroll
        for (int nt = 0; nt < 4; ++nt) wf[nt] = wn[nt];
      }
      packY(Y1, 512, 120, n0, P.b1[g], ac);
    }
  }
  __syncthreads();  // Y1 complete; Xs dead

  // ---- fc2: Y2 = relu(Y1 @ W2p^T + b2); K=1024 perm; N=1024, 2 passes ----
  {
    const unsigned short* W2 = P.w2[g];
    for (int p = 0; p < 2; ++p) {
      const int n0 = p * 512 + w * 64;
      const unsigned short* w2p = W2 + (size_t)(n0 + l15) * 1024 + q * 8;
      f32x4 ac[4];
#pragma unroll
      for (int nt = 0; nt < 4; ++nt) ac[nt] = f32x4{0.f, 0.f, 0.f, 0.f};
      b16x8 wf[4], wn[4];
#pragma unroll
      for (int nt = 0; nt < 4; ++nt) wf[nt] = ld8(w2p + nt * 16 * 1024);
      for (int j = 0; j < 32; ++j) {
        if (j + 1 < 32) {
#pragma unroll
          for (int nt = 0; nt < 4; ++nt)
            wn[nt] = ld8(w2p + nt * 16 * 1024 + (j + 1) * 32);
        }
        b16x8 a = aY(Y1, 512, 120, j);
#pragma unroll
        for (int nt = 0; nt < 4; ++nt) ac[nt] = mfma_bf16(a, wf[nt], ac[nt]);
#pragma unroll
        for (int nt = 0; nt < 4; ++nt) wf[nt] = wn[nt];
      }
      packY(Y2, 512, 120, n0, P.b2[g], ac);
    }
  }
  __syncthreads();  // Y2 complete; Y1 dead

  // ---- fc3: Y3 = relu(Y2 @ W3p^T + b3); K=1024 perm; N=512, 1 pass ----
  {
    const unsigned short* W3 = P.w3[g];
    const int n0 = w * 64;
    const unsigned short* w3p = W3 + (size_t)(n0 + l15) * 1024 + q * 8;
    f32x4 ac[4];
#pragma unroll
    for (int nt = 0; nt < 4; ++nt) ac[nt] = f32x4{0.f, 0.f, 0.f, 0.f};
    b16x8 wf[4], wn[4];
#pragma unroll
    for (int nt = 0; nt < 4; ++nt) wf[nt] = ld8(w3p + nt * 16 * 1024);
    for (int j = 0; j < 32; ++j) {
      if (j + 1 < 32) {
#pragma unroll
        for (int nt = 0; nt < 4; ++nt)
          wn[nt] = ld8(w3p + nt * 16 * 1024 + (j + 1) * 32);
      }
      b16x8 a = aY(Y2, 512, 120, j);
#pragma unroll
      for (int nt = 0; nt < 4; ++nt) ac[nt] = mfma_bf16(a, wf[nt], ac[nt]);
#pragma unroll
      for (int nt = 0; nt < 4; ++nt) wf[nt] = wn[nt];
    }
    packY(Y3, 256, 56, n0, P.b3[g], ac);
  }
  __syncthreads();  // Y3 complete; Y2 dead

  // ---- fc4 + q: out = qb + qw . relu(Y3 @ W4p^T + b4); K=512 perm ----
  {
    const unsigned short* W4 = P.w4[g];
    const int n0 = w * 32;
    const unsigned short* w4p = W4 + (size_t)(n0 + l15) * 512 + q * 8;
    f32x4 ac[2];
#pragma unroll
    for (int nt = 0; nt < 2; ++nt) ac[nt] = f32x4{0.f, 0.f, 0.f, 0.f};
    b16x8 wf[2], wn[2];
#pragma unroll
    for (int nt = 0; nt < 2; ++nt) wf[nt] = ld8(w4p + nt * 16 * 512);
    for (int j = 0; j < 16; ++j) {
      if (j + 1 < 16) {
#pragma unroll
        for (int nt = 0; nt < 2; ++nt)
          wn[nt] = ld8(w4p + nt * 16 * 512 + (j + 1) * 32);
      }
      b16x8 a = aY(Y3, 256, 56, j);
#pragma unroll
      for (int nt = 0; nt < 2; ++nt) ac[nt] = mfma_bf16(a, wf[nt], ac[nt]);
#pragma unroll
      for (int nt = 0; nt < 2; ++nt) wf[nt] = wn[nt];
    }
    const float* b4 = P.b4[g];
    const float* qwp = P.qw[g];
#pragma unroll
    for (int rg = 0; rg < 4; ++rg) {
      float s = 0.f;
#pragma unroll
      for (int nt = 0; nt < 2; ++nt) {
        const int col = n0 + nt * 16 + l15;
        s += fmaxf(ac[nt][rg] + b4[col], 0.f) * qwp[col];
      }
#pragma unroll
      for (int off = 1; off < 16; off <<= 1) s += __shfl_xor(s, off);
      if (l15 == 0) red[(q * 4 + rg) * 8 + w] = s;
    }
  }
  __syncthreads();
  if (tid < 16) {
    float s = 0.f;
#pragma unroll
    for (int i = 0; i < 8; ++i) s += red[tid * 8 + i];
    P.out[(size_t)g * 2048 + r0 + tid] = P.qb[g][0] + s;
  }
}

// ---------- host ----------
extern "C" void kernel_launch(void* const* d_in, const int* in_sizes, int n_in,
                              void* d_out, int out_size, void* d_ws, size_t ws_size,
                              hipStream_t stream) {
  const float* state   = (const float*)d_in[0];
  const float* action  = (const float*)d_in[1];
  const int*   lengths = (const int*)d_in[2];
  const float* g_wih[2] = {(const float*)d_in[3], (const float*)d_in[17]};
  const float* g_whh[2] = {(const float*)d_in[4], (const float*)d_in[18]};
  const float* g_bih[2] = {(const float*)d_in[5], (const float*)d_in[19]};
  const float* g_bhh[2] = {(const float*)d_in[6], (const float*)d_in[20]};
  const float* fcw[2][4] = {
      {(const float*)d_in[7], (const float*)d_in[9], (const float*)d_in[11], (const float*)d_in[13]},
      {(const float*)d_in[21], (const float*)d_in[23], (const float*)d_in[25], (const float*)d_in[27]}};
  const float* fcb[2][4] = {
      {(const float*)d_in[8], (const float*)d_in[10], (const float*)d_in[12], (const float*)d_in[14]},
      {(const float*)d_in[22], (const float*)d_in[24], (const float*)d_in[26], (const float*)d_in[28]}};
  const float* qw[2] = {(const float*)d_in[15], (const float*)d_in[29]};
  const float* qb[2] = {(const float*)d_in[16], (const float*)d_in[30]};
  float* out = (float*)d_out;

  uintptr_t base = (uintptr_t)d_ws;
  auto alloc = [&](size_t bytes) -> unsigned short* {
    void* p = (void*)base;
    base += (bytes + 255) & ~(size_t)255;
    return (unsigned short*)p;
  };
  unsigned short *waug[2], *w1b[2], *w2b[2], *w3b[2], *w4b[2];
  for (int g = 0; g < 2; g++) waug[g] = alloc(768 * 288 * 2);
  for (int g = 0; g < 2; g++) w1b[g] = alloc(1024 * 288 * 2);
  for (int g = 0; g < 2; g++) w2b[g] = alloc(1024 * 1024 * 2);
  for (int g = 0; g < 2; g++) w3b[g] = alloc(512 * 1024 * 2);
  for (int g = 0; g < 2; g++) w4b[g] = alloc(256 * 512 * 2);
  (void)ws_size; (void)in_sizes; (void)n_in; (void)out_size;

  PrepArgs pa;
  for (int g = 0; g < 2; g++) {
    pa.whh[g] = g_whh[g]; pa.wih[g] = g_wih[g];
    pa.bih[g] = g_bih[g]; pa.bhh[g] = g_bhh[g];
    pa.waug[g] = waug[g];
    pa.src[g][0] = fcw[g][0]; pa.dst[g][0] = w1b[g];
    pa.src[g][1] = fcw[g][1]; pa.dst[g][1] = w2b[g];
    pa.src[g][2] = fcw[g][2]; pa.dst[g][2] = w3b[g];
    pa.src[g][3] = fcw[g][3]; pa.dst[g][3] = w4b[g];
  }
  prep_kernel<<<dim3(512, 10), 256, 0, stream>>>(pa);

  FusedArgs fa;
  fa.state = state; fa.action = action; fa.lengths = lengths;
  for (int g = 0; g < 2; g++) {
    fa.waug[g] = waug[g]; fa.bhh[g] = g_bhh[g];
    fa.w1[g] = w1b[g]; fa.w2[g] = w2b[g]; fa.w3[g] = w3b[g]; fa.w4[g] = w4b[g];
    fa.b1[g] = fcb[g][0]; fa.b2[g] = fcb[g][1];
    fa.b3[g] = fcb[g][2]; fa.b4[g] = fcb[g][3];
    fa.qw[g] = qw[g]; fa.qb[g] = qb[g];
  }
  fa.out = out;
  (void)hipFuncSetAttribute((const void*)fused_kernel,
                            hipFuncAttributeMaxDynamicSharedMemorySize,
                            FUSED_LDS_BYTES);
  fused_kernel<<<dim3(256), dim3(512), FUSED_LDS_BYTES, stream>>>(fa);
}

// Round 11
// 294.074 us; speedup vs baseline: 1.2729x; 1.2729x over previous
//
#include <hip/hip_runtime.h>

// ---------- types ----------
typedef float  f32x4 __attribute__((ext_vector_type(4)));
typedef short  s16x8 __attribute__((ext_vector_type(8)));
typedef __bf16 b16x8 __attribute__((ext_vector_type(8)));
typedef unsigned u32x4 __attribute__((ext_vector_type(4)));

#define DEV __device__ __forceinline__

DEV unsigned short f2b(float f) {           // fp32 -> bf16 RNE
  unsigned u = __builtin_bit_cast(unsigned, f);
  u = (u + 0x7FFFu + ((u >> 16) & 1u)) >> 16;
  return (unsigned short)u;
}
DEV unsigned cvt_pk_bf16(float lo, float hi) {  // packed RNE bf16 pair
  unsigned r;
  asm("v_cvt_pk_bf16_f32 %0, %1, %2" : "=v"(r) : "v"(lo), "v"(hi));
  return r;
}
DEV b16x8 ld8(const unsigned short* p) {    // 16B fragment load + reinterpret
  return __builtin_bit_cast(b16x8, *(const s16x8*)p);
}
DEV float sigm(float x) { return __builtin_amdgcn_rcpf(1.f + __expf(-x)); }
DEV float tanh_fast(float x) {
  float e = __expf(2.f * x);                // overflow-safe: e=inf -> 1, e=0 -> -1
  return 1.f - 2.f * __builtin_amdgcn_rcpf(e + 1.f);
}
DEV void async16(const unsigned short* g, unsigned short* l) {
  __builtin_amdgcn_global_load_lds(
      (const __attribute__((address_space(1))) unsigned int*)g,
      (__attribute__((address_space(3))) unsigned int*)l, 16, 0, 0);
}
DEV f32x4 mfma_bf16(b16x8 a, b16x8 b, f32x4 c) {
  return __builtin_amdgcn_mfma_f32_16x16x32_bf16(a, b, c, 0, 0, 0);
}

// ---------- prep: fp32->bf16 weight conversion, VECTORIZED ----------
// 8-wide items, compile-time divisors only, float4 loads, 16B stores.
// Waug [768][288] = [Whh k-permuted | Wih | bias@271 | 0]. The k-perm
// (out pos 32w+2t+s <- col 32w+t+16s) is a lo/hi zip: for an 8-wide output at
// c0, out[2m]/out[2m+1] = in[base32+i0+m] / in[base32+16+i0+m] -- exactly two
// aligned float4 loads + 4 cvt_pk.
struct PrepArgs {
  const float *whh[2], *wih[2], *bih[2], *bhh[2];
  const float *src[2][4];               // fc1..fc4 fp32 weights per branch
  unsigned short *waug[2], *dst[2][4];  // bf16 outputs
  const float *qb[2];
  float *out;                           // prefill with qb (fc4q atomically adds)
};

template <int ROWS, int SC, int DC>
DEV void prep_fc_pad(const float* __restrict__ src,
                     unsigned short* __restrict__ dst, int i0, int stride) {
  constexpr int IPR = DC / 8;           // items per row (literal divisor)
  for (int i8 = i0; i8 < ROWS * IPR; i8 += stride) {
    const int r = i8 / IPR, it = i8 - r * IPR;
    const int c0 = it * 8;
    u32x4 hp;
    if (c0 + 8 <= SC) {
      const float* bp = src + (size_t)r * SC + c0;
      const float4 a = *(const float4*)bp;
      const float4 b = *(const float4*)(bp + 4);
      hp = u32x4{cvt_pk_bf16(a.x, a.y), cvt_pk_bf16(a.z, a.w),
                 cvt_pk_bf16(b.x, b.y), cvt_pk_bf16(b.z, b.w)};
    } else {
      hp = u32x4{0u, 0u, 0u, 0u};
    }
    *(u32x4*)(dst + (size_t)i8 * 8) = hp;
  }
}

DEV void prep_fc_flat(const float* __restrict__ src,
                      unsigned short* __restrict__ dst, int n8, int i0,
                      int stride) {
  for (int i8 = i0; i8 < n8; i8 += stride) {
    const float4 a = *(const float4*)(src + (size_t)i8 * 8);
    const float4 b = *(const float4*)(src + (size_t)i8 * 8 + 4);
    u32x4 hp = {cvt_pk_bf16(a.x, a.y), cvt_pk_bf16(a.z, a.w),
                cvt_pk_bf16(b.x, b.y), cvt_pk_bf16(b.z, b.w)};
    *(u32x4*)(dst + (size_t)i8 * 8) = hp;
  }
}

__global__ __launch_bounds__(256) void prep_kernel(PrepArgs p) {
  const int job = blockIdx.y;
  const int i0 = blockIdx.x * 256 + threadIdx.x;   // vec8 item index
  const int stride = gridDim.x * 256;
  if (job < 2) {
    const float* whh = p.whh[job];
    const float* wih = p.wih[job];
    const float* bih = p.bih[job];
    const float* bhh = p.bhh[job];
    unsigned short* dst = p.waug[job];
    for (int i8 = i0; i8 < 768 * 36; i8 += stride) {
      const int j = i8 / 36, it = i8 - j * 36;     // literal divisor
      u32x4 hp;
      if (it < 32) {                               // Whh k-permuted (zip)
        const int c0 = it * 8;
        const int base32 = c0 & ~31;
        const int ii = (c0 & 31) >> 1;             // 0,4,8,12 -> f4-aligned
        const float* bp = whh + (size_t)j * 256 + base32 + ii;
        const float4 lo = *(const float4*)bp;
        const float4 hi = *(const float4*)(bp + 16);
        hp = u32x4{cvt_pk_bf16(lo.x, hi.x), cvt_pk_bf16(lo.y, hi.y),
                   cvt_pk_bf16(lo.z, hi.z), cvt_pk_bf16(lo.w, hi.w)};
      } else if (it == 32) {                       // cols 256..263 = wih 0..7
        const float* wp = wih + (size_t)j * 15;
        hp = u32x4{cvt_pk_bf16(wp[0], wp[1]), cvt_pk_bf16(wp[2], wp[3]),
                   cvt_pk_bf16(wp[4], wp[5]), cvt_pk_bf16(wp[6], wp[7])};
      } else if (it == 33) {                       // wih 8..14 + bias@271
        const float* wp = wih + (size_t)j * 15;
        const float b271 = (j < 512) ? (bih[j] + bhh[j]) : bih[j];
        hp = u32x4{cvt_pk_bf16(wp[8], wp[9]), cvt_pk_bf16(wp[10], wp[11]),
                   cvt_pk_bf16(wp[12], wp[13]), cvt_pk_bf16(wp[14], b271)};
      } else {                                     // 272..287 zero pad
        hp = u32x4{0u, 0u, 0u, 0u};
      }
      *(u32x4*)(dst + (size_t)i8 * 8) = hp;
    }
  } else if (job == 2) {
    prep_fc_pad<1024, 272, 288>(p.src[0][0], p.dst[0][0], i0, stride);
  } else if (job == 3) {
    prep_fc_flat(p.src[0][1], p.dst[0][1], 1024 * 128, i0, stride);
  } else if (job == 4) {
    prep_fc_flat(p.src[0][2], p.dst[0][2], 512 * 128, i0, stride);
  } else if (job == 5) {
    prep_fc_flat(p.src[0][3], p.dst[0][3], 256 * 64, i0, stride);
  } else if (job == 6) {
    prep_fc_pad<1024, 272, 288>(p.src[1][0], p.dst[1][0], i0, stride);
  } else if (job == 7) {
    prep_fc_flat(p.src[1][1], p.dst[1][1], 1024 * 128, i0, stride);
  } else if (job == 8) {
    prep_fc_flat(p.src[1][2], p.dst[1][2], 512 * 128, i0, stride);
  } else if (job == 9) {
    prep_fc_flat(p.src[1][3], p.dst[1][3], 256 * 64, i0, stride);
  } else {
    for (int idx = i0; idx < 4096; idx += stride)
      p.out[idx] = p.qb[idx >> 11][0];
  }
}

// ---------- persistent fused GRU (R1/R3 structure: verified ~142 us) ----------
#define GRU_LDS_BYTES 147584
__global__ __launch_bounds__(512, 2) void gru_kernel(
    const float* __restrict__ state, const float* __restrict__ action,
    const int* __restrict__ lengths,
    const unsigned short* __restrict__ waug0, const unsigned short* __restrict__ waug1,
    const float* __restrict__ bhh0, const float* __restrict__ bhh1,
    unsigned short* __restrict__ x0, unsigned short* __restrict__ x1) {
  extern __shared__ char smem[];
  unsigned short* W67L = (unsigned short*)smem;             // 96 KB arena
  unsigned short* SgL  = (unsigned short*)(smem + 98304);   // 32 KB state frags
  unsigned*       Hb2  = (unsigned*)(smem + 131072);        // 2 x 16 x 128 dw
  int* lenS = (int*)(smem + 147456);
  int* mlS  = (int*)(smem + 147520);
  float* tmpF = (float*)smem;                               // phase-a overlay

  const int tid = threadIdx.x;
  const int lane = tid & 63, w = tid >> 6;
  const int l15 = lane & 15, q = lane >> 4;
  const int g = blockIdx.x & 1;
  const int r0 = (blockIdx.x >> 1) * 16;

  const unsigned short* Waug = g ? waug1 : waug0;
  const float* bhh = g ? bhh1 : bhh0;
  unsigned short* xout = g ? x1 : x0;

  // ---- phase a: state tile fp32 -> LDS (coalesced, stride-962 rows) ----
  {
    const float2* src = (const float2*)(state + (size_t)r0 * 960);
    float2* dstv = (float2*)tmpF;
    for (int i = tid; i < 7680; i += 512) {
      const int row = i / 480;                    // 480 float2 per source row
      dstv[row * 481 + (i - row * 480)] = src[i]; // dst stride 481 f2 = 962 f
    }
  }
  for (int i = tid; i < 4096; i += 512) Hb2[i] = 0;
  if (tid < 16) lenS[tid] = lengths[r0 + tid];
  __syncthreads();
  if (tid == 0) {
    int m = 1;
    for (int i = 0; i < 16; i++) m = lenS[i] > m ? lenS[i] : m;
    *mlS = m;
  }

  // ---- phase b: SgL[t][L] = aug A-fragment (state 15 | 1.0 | 0) ----
  for (int s = tid; s < 64 * 32; s += 512) {
    const int t = s >> 5, L = s & 31;
    const int q2 = L >> 4, r = L & 15;
    const float* bp = tmpF + r * 962 + t * 15;
    unsigned hp[4];
#pragma unroll
    for (int jp = 0; jp < 4; jp++) {
      const int k0 = q2 * 8 + 2 * jp;
      float lo = (k0 < 15) ? bp[k0] : (k0 == 15 ? 1.0f : 0.f);
      float hi = (k0 + 1 < 15) ? bp[k0 + 1] : (k0 + 1 == 15 ? 1.0f : 0.f);
      hp[jp] = cvt_pk_bf16(lo, hi);
    }
    *(u32x4*)(SgL + (size_t)s * 8) = u32x4{hp[0], hp[1], hp[2], hp[3]};
  }
  __syncthreads();  // tmpF dead; arena may be filled

  // ---- phase c: resident weights + arena fill ----
  int c0[6];
  c0[0] = 32 * w;       c0[1] = 32 * w + 16;
  c0[2] = 256 + 32 * w; c0[3] = 256 + 32 * w + 16;
  c0[4] = 512 + 32 * w; c0[5] = 512 + 32 * w + 16;

  b16x8 wres[6][6];   // h ksteps 0..5
  b16x8 waugf[6];     // aug kstep
#pragma unroll
  for (int i = 0; i < 6; i++) {
    const unsigned short* bpi = Waug + (size_t)(c0[i] + l15) * 288 + q * 8;
#pragma unroll
    for (int j = 0; j < 6; j++) wres[i][j] = ld8(bpi + j * 32);
    waugf[i] = ld8(bpi + 256);
#pragma unroll
    for (int ks2 = 0; ks2 < 2; ks2++) {
      b16x8 v = ld8(bpi + (6 + ks2) * 32);
      *(s16x8*)(W67L + (size_t)(ks2 * 6 + i) * 4096 + tid * 8) =
          __builtin_bit_cast(s16x8, v);
    }
  }
  float bnH[2] = {bhh[c0[4] + l15], bhh[c0[5] + l15]};
  int len4[4];
#pragma unroll
  for (int r = 0; r < 4; r++) len4[r] = lenS[q * 4 + r];

  int aOff[8];
#pragma unroll
  for (int j = 0; j < 8; j++) {
    const int cj = 4 * j + q;
    const int pj = (cj & 24) | ((cj & 7) ^ (l15 & 7));
    aOff[j] = l15 * 128 + pj * 4;
  }
  int wOff[4];
#pragma unroll
  for (int rg = 0; rg < 4; rg++) {
    const int row = q * 4 + rg;
    const int cb = 4 * w + (l15 >> 2);
    const int pw = (cb & 24) | ((cb & 7) ^ (row & 7));
    wOff[rg] = row * 128 + pw * 4 + (l15 & 3);
  }
  __syncthreads();
  const int maxlen = *mlS;

  float hold[2][4] = {{0, 0, 0, 0}, {0, 0, 0, 0}};
  int poff = 0;

  for (int t = 0; t < maxlen; ++t) {
    f32x4 acc[6];
    {
      s16x8 raw = *(const s16x8*)(SgL + t * 256 + ((q & 1) * 16 + l15) * 8);
      b16x8 a8 = __builtin_bit_cast(b16x8, raw);
      const f32x4 z4 = {0.f, 0.f, 0.f, 0.f};
#pragma unroll
      for (int i = 0; i < 6; i++) acc[i] = mfma_bf16(a8, waugf[i], z4);
    }
    f32x4 giN0 = acc[4], giN1 = acc[5];
    acc[4] = acc[4] + bnH[0];
    acc[5] = acc[5] + bnH[1];

    __syncthreads();

    const unsigned* hb = Hb2 + poff;
#pragma unroll
    for (int j = 0; j < 6; j++) {
      b16x8 a = __builtin_bit_cast(b16x8, *(const uint4*)(hb + aOff[j]));
#pragma unroll
      for (int i = 0; i < 6; i++) acc[i] = mfma_bf16(a, wres[i][j], acc[i]);
    }
#pragma unroll
    for (int ks2 = 0; ks2 < 2; ks2++) {
      b16x8 a = __builtin_bit_cast(b16x8, *(const uint4*)(hb + aOff[6 + ks2]));
#pragma unroll
      for (int i = 0; i < 6; i++) {
        b16x8 bw = ld8(W67L + (size_t)(ks2 * 6 + i) * 4096 + tid * 8);
        acc[i] = mfma_bf16(a, bw, acc[i]);
      }
    }

    unsigned* hbw = Hb2 + (poff ^ 2048);
#pragma unroll
    for (int rg = 0; rg < 4; rg++) {
      const bool live = (t < len4[rg]);
      float r0g = sigm(acc[0][rg]);
      float z0 = sigm(acc[2][rg]);
      float n0 = tanh_fast(giN0[rg] + r0g * (acc[4][rg] - giN0[rg]));
      float h0 = n0 + z0 * (hold[0][rg] - n0);
      h0 = live ? h0 : hold[0][rg];
      hold[0][rg] = h0;
      float r1g = sigm(acc[1][rg]);
      float z1 = sigm(acc[3][rg]);
      float n1 = tanh_fast(giN1[rg] + r1g * (acc[5][rg] - giN1[rg]));
      float h1 = n1 + z1 * (hold[1][rg] - n1);
      h1 = live ? h1 : hold[1][rg];
      hold[1][rg] = h1;
      hbw[wOff[rg]] = cvt_pk_bf16(h0, h1);
    }
    poff ^= 2048;
  }

  // emit x = [state[:,0,:], action, h, 0-pad] bf16 [16][288]
#pragma unroll
  for (int i = 0; i < 2; i++) {
    const int c = 32 * w + 16 * i + l15;
#pragma unroll
    for (int rg = 0; rg < 4; rg++) {
      const int row = q * 4 + rg;
      xout[(size_t)(r0 + row) * 288 + 16 + c] = f2b(hold[i][rg]);
    }
  }
  {
    const int row = tid >> 5, cc = tid & 31;
    float v; int col;
    if (cc < 15)       { v = state[(size_t)(r0 + row) * 960 + cc]; col = cc; }
    else if (cc == 15) { v = action[r0 + row]; col = 15; }
    else               { v = 0.f; col = 256 + cc; }
    xout[(size_t)(r0 + row) * 288 + col] = f2b(v);
  }
}

// ---------- bf16 GEMM: Y = relu(A @ W^T + b); 2-phase prefetch (dbuf LDS) ----
template <int BM, int BN>
__global__ __launch_bounds__(256, 2) void gemm_bias_relu(
    const unsigned short* __restrict__ A0, const unsigned short* __restrict__ A1,
    const unsigned short* __restrict__ W0, const unsigned short* __restrict__ W1,
    const float* __restrict__ b0, const float* __restrict__ b1,
    unsigned short* __restrict__ Y0, unsigned short* __restrict__ Y1,
    int N, int K) {
  const unsigned short* A = blockIdx.z ? A1 : A0;
  const unsigned short* W = blockIdx.z ? W1 : W0;
  const float* bias = blockIdx.z ? b1 : b0;
  unsigned short* Y = blockIdx.z ? Y1 : Y0;

  constexpr int MT = BM / 32;
  constexpr int NT = BN / 32;
  const int tid = threadIdx.x;
  const int lane = tid & 63, wid = tid >> 6;
  const int wm = wid >> 1, wn = wid & 1;
  const int l15 = lane & 15, q = lane >> 4;
  const int m0 = blockIdx.x * BM, n0 = blockIdx.y * BN;

  __shared__ unsigned short As[2][BM * 32];
  __shared__ unsigned short Bs[2][BN * 32];

  f32x4 acc[MT][NT];
#pragma unroll
  for (int mi = 0; mi < MT; mi++)
#pragma unroll
    for (int ni = 0; ni < NT; ni++) acc[mi][ni] = f32x4{0.f, 0.f, 0.f, 0.f};

  const int srow = tid >> 2, scol = (tid & 3) * 8;
  const int nk = K >> 5;

  // prologue: stage tile 0 into buf 0
#pragma unroll
  for (int g64 = 0; g64 < BM / 64; g64++)
    async16(A + (size_t)(m0 + g64 * 64 + srow) * K + scol,
            &As[0][g64 * 2048 + tid * 8]);
#pragma unroll
  for (int g64 = 0; g64 < BN / 64; g64++)
    async16(W + (size_t)(n0 + g64 * 64 + srow) * K + scol,
            &Bs[0][g64 * 2048 + tid * 8]);
  __syncthreads();

  for (int t = 0; t < nk; ++t) {
    const int cur = t & 1;
    if (t + 1 < nk) {  // stage next tile into the other buffer
      const int k1 = (t + 1) * 32;
#pragma unroll
      for (int g64 = 0; g64 < BM / 64; g64++)
        async16(A + (size_t)(m0 + g64 * 64 + srow) * K + scol + k1,
                &As[cur ^ 1][g64 * 2048 + tid * 8]);
#pragma unroll
      for (int g64 = 0; g64 < BN / 64; g64++)
        async16(W + (size_t)(n0 + g64 * 64 + srow) * K + scol + k1,
                &Bs[cur ^ 1][g64 * 2048 + tid * 8]);
    }

    b16x8 af[MT], bf[NT];
#pragma unroll
    for (int mi = 0; mi < MT; mi++)
      af[mi] = ld8(&As[cur][(wm * (BM / 2) + mi * 16 + l15) * 32 + q * 8]);
#pragma unroll
    for (int ni = 0; ni < NT; ni++)
      bf[ni] = ld8(&Bs[cur][(wn * (BN / 2) + ni * 16 + l15) * 32 + q * 8]);
#pragma unroll
    for (int mi = 0; mi < MT; mi++)
#pragma unroll
      for (int ni = 0; ni < NT; ni++)
        acc[mi][ni] = mfma_bf16(af[mi], bf[ni], acc[mi][ni]);
    __syncthreads();
  }

#pragma unroll
  for (int ni = 0; ni < NT; ni++) {
    const int col = n0 + wn * (BN / 2) + ni * 16 + l15;
    const float bv = bias[col];
#pragma unroll
    for (int mi = 0; mi < MT; mi++) {
      const int rbase = m0 + wm * (BM / 2) + mi * 16 + q * 4;
#pragma unroll
      for (int rg = 0; rg < 4; rg++) {
        float v = acc[mi][ni][rg] + bv;
        v = fmaxf(v, 0.f);
        Y[(size_t)(rbase + rg) * N + col] = f2b(v);
      }
    }
  }
}

// ---------- fc4 + q fused: out[b] += qw . relu(y3[b] @ W4^T + b4) ----------
__global__ __launch_bounds__(256, 2) void fc4q_kernel(
    const unsigned short* __restrict__ A0, const unsigned short* __restrict__ A1,
    const unsigned short* __restrict__ W0, const unsigned short* __restrict__ W1,
    const float* __restrict__ b0, const float* __restrict__ b1,
    const float* __restrict__ qw0, const float* __restrict__ qw1,
    float* __restrict__ out) {
  const unsigned short* A = blockIdx.z ? A1 : A0;
  const unsigned short* W = blockIdx.z ? W1 : W0;
  const float* bias = blockIdx.z ? b1 : b0;
  const float* qw = blockIdx.z ? qw1 : qw0;

  const int tid = threadIdx.x;
  const int lane = tid & 63, wn = tid >> 6;      // 4 waves = 4 n-quarters
  const int l15 = lane & 15, q = lane >> 4;
  const int m0 = blockIdx.x * 32;
  const int nbase = blockIdx.y * 128;            // n-half
  const int K = 512;

  __shared__ unsigned short As[2][32 * 32];
  __shared__ unsigned short Bs[2][128 * 32];
  __shared__ float red[32][4];

  f32x4 acc[2][2];
#pragma unroll
  for (int mi = 0; mi < 2; mi++)
#pragma unroll
    for (int ni = 0; ni < 2; ni++) acc[mi][ni] = f32x4{0.f, 0.f, 0.f, 0.f};

  const int srow = tid >> 2, scol = (tid & 3) * 8;
  const int nk = K >> 5;  // 16

  if (tid < 128)
    async16(A + (size_t)(m0 + srow) * K + scol, &As[0][tid * 8]);
#pragma unroll
  for (int g64 = 0; g64 < 2; g64++)
    async16(W + (size_t)(nbase + g64 * 64 + srow) * K + scol,
            &Bs[0][g64 * 2048 + tid * 8]);
  __syncthreads();

  for (int t = 0; t < nk; ++t) {
    const int cur = t & 1;
    if (t + 1 < nk) {
      const int k1 = (t + 1) * 32;
      if (tid < 128)
        async16(A + (size_t)(m0 + srow) * K + scol + k1, &As[cur ^ 1][tid * 8]);
#pragma unroll
      for (int g64 = 0; g64 < 2; g64++)
        async16(W + (size_t)(nbase + g64 * 64 + srow) * K + scol + k1,
                &Bs[cur ^ 1][g64 * 2048 + tid * 8]);
    }

    b16x8 af[2], bf[2];
#pragma unroll
    for (int mi = 0; mi < 2; mi++)
      af[mi] = ld8(&As[cur][(mi * 16 + l15) * 32 + q * 8]);
#pragma unroll
    for (int ni = 0; ni < 2; ni++)
      bf[ni] = ld8(&Bs[cur][(wn * 32 + ni * 16 + l15) * 32 + q * 8]);
#pragma unroll
    for (int mi = 0; mi < 2; mi++)
#pragma unroll
      for (int ni = 0; ni < 2; ni++)
        acc[mi][ni] = mfma_bf16(af[mi], bf[ni], acc[mi][ni]);
    __syncthreads();
  }

  // partial q-dot over this wave's 32 cols
#pragma unroll
  for (int mi = 0; mi < 2; mi++) {
#pragma unroll
    for (int rg = 0; rg < 4; rg++) {
      float s = 0.f;
#pragma unroll
      for (int ni = 0; ni < 2; ni++) {
        const int col = nbase + wn * 32 + ni * 16 + l15;
        float v = fmaxf(acc[mi][ni][rg] + bias[col], 0.f);
        s += v * qw[col];
      }
#pragma unroll
      for (int off = 1; off < 16; off <<= 1) s += __shfl_xor(s, off);
      if (l15 == 0) red[mi * 16 + q * 4 + rg][wn] = s;
    }
  }
  __syncthreads();
  if (tid < 32) {
    float t = red[tid][0] + red[tid][1] + red[tid][2] + red[tid][3];
    atomicAdd(out + (size_t)blockIdx.z * 2048 + m0 + tid, t);
  }
}

// ---------- host ----------
extern "C" void kernel_launch(void* const* d_in, const int* in_sizes, int n_in,
                              void* d_out, int out_size, void* d_ws, size_t ws_size,
                              hipStream_t stream) {
  const float* state   = (const float*)d_in[0];
  const float* action  = (const float*)d_in[1];
  const int*   lengths = (const int*)d_in[2];
  const float* g_wih[2] = {(const float*)d_in[3], (const float*)d_in[17]};
  const float* g_whh[2] = {(const float*)d_in[4], (const float*)d_in[18]};
  const float* g_bih[2] = {(const float*)d_in[5], (const float*)d_in[19]};
  const float* g_bhh[2] = {(const float*)d_in[6], (const float*)d_in[20]};
  const float* fcw[2][4] = {
      {(const float*)d_in[7], (const float*)d_in[9], (const float*)d_in[11], (const float*)d_in[13]},
      {(const float*)d_in[21], (const float*)d_in[23], (const float*)d_in[25], (const float*)d_in[27]}};
  const float* fcb[2][4] = {
      {(const float*)d_in[8], (const float*)d_in[10], (const float*)d_in[12], (const float*)d_in[14]},
      {(const float*)d_in[22], (const float*)d_in[24], (const float*)d_in[26], (const float*)d_in[28]}};
  const float* qw[2] = {(const float*)d_in[15], (const float*)d_in[29]};
  const float* qb[2] = {(const float*)d_in[16], (const float*)d_in[30]};
  float* out = (float*)d_out;

  uintptr_t base = (uintptr_t)d_ws;
  auto alloc = [&](size_t bytes) -> unsigned short* {
    void* p = (void*)base;
    base += (bytes + 255) & ~(size_t)255;
    return (unsigned short*)p;
  };
  unsigned short *waug[2], *w1b[2], *w2b[2], *w3b[2], *w4b[2], *xb[2], *yA[2], *yB[2];
  for (int g = 0; g < 2; g++) waug[g] = alloc(768 * 288 * 2);
  for (int g = 0; g < 2; g++) w1b[g] = alloc(1024 * 288 * 2);
  for (int g = 0; g < 2; g++) w2b[g] = alloc(1024 * 1024 * 2);
  for (int g = 0; g < 2; g++) w3b[g] = alloc(512 * 1024 * 2);
  for (int g = 0; g < 2; g++) w4b[g] = alloc(256 * 512 * 2);
  for (int g = 0; g < 2; g++) xb[g] = alloc(2048 * 288 * 2);
  for (int g = 0; g < 2; g++) yA[g] = alloc(2048 * 1024 * 2);
  for (int g = 0; g < 2; g++) yB[g] = alloc(2048 * 1024 * 2);
  (void)ws_size; (void)in_sizes; (void)n_in; (void)out_size;

  PrepArgs pa;
  for (int g = 0; g < 2; g++) {
    pa.whh[g] = g_whh[g]; pa.wih[g] = g_wih[g];
    pa.bih[g] = g_bih[g]; pa.bhh[g] = g_bhh[g];
    pa.waug[g] = waug[g];
    pa.src[g][0] = fcw[g][0]; pa.dst[g][0] = w1b[g];
    pa.src[g][1] = fcw[g][1]; pa.dst[g][1] = w2b[g];
    pa.src[g][2] = fcw[g][2]; pa.dst[g][2] = w3b[g];
    pa.src[g][3] = fcw[g][3]; pa.dst[g][3] = w4b[g];
    pa.qb[g] = qb[g];
  }
  pa.out = out;
  prep_kernel<<<dim3(512, 11), 256, 0, stream>>>(pa);

  (void)hipFuncSetAttribute((const void*)gru_kernel,
                            hipFuncAttributeMaxDynamicSharedMemorySize,
                            GRU_LDS_BYTES);
  gru_kernel<<<dim3(256), dim3(512), GRU_LDS_BYTES, stream>>>(
      state, action, lengths, waug[0], waug[1], g_bhh[0], g_bhh[1], xb[0], xb[1]);

  gemm_bias_relu<64, 128><<<dim3(32, 8, 2), 256, 0, stream>>>(
      xb[0], xb[1], w1b[0], w1b[1], fcb[0][0], fcb[1][0], yA[0], yA[1], 1024, 288);
  gemm_bias_relu<64, 128><<<dim3(32, 8, 2), 256, 0, stream>>>(
      yA[0], yA[1], w2b[0], w2b[1], fcb[0][1], fcb[1][1], yB[0], yB[1], 1024, 1024);
  gemm_bias_relu<64, 64><<<dim3(32, 8, 2), 256, 0, stream>>>(
      yB[0], yB[1], w3b[0], w3b[1], fcb[0][2], fcb[1][2], yA[0], yA[1], 512, 1024);
  fc4q_kernel<<<dim3(64, 2, 2), 256, 0, stream>>>(
      yA[0], yA[1], w4b[0], w4b[1], fcb[0][3], fcb[1][3], qw[0], qw[1], out);
}